// Round 2
// baseline (14931.432 us; speedup 1.0000x reference)
//
#include <hip/hip_runtime.h>
#include <cstdint>
#include <cstddef>

#define HDIM 2048
#define NCLS 11
#define NBLK 256
#define NTHR 256
#define EPB  (HDIM / NBLK)   // 8 h-elements per block

// d_ws layout (bytes):
//   [0,     4096)  barrier state (memsetAsync to 0 at the top of every launch)
//   [4096, 12288)  hwork: working h vector (2048 f32)      [if ws big enough]
//   [16384, +64Mi) Wc = W_ih + W_hh                         [if ws big enough]
#define BAR_BYTES 4096
// barrier word offsets (in uint32 units; 16-uint = 64 B padding per counter)
#define OFF_GCNT(g)  ((g) * 16)        // 8 group arrival counters
#define OFF_ALLC     (128)             // global arrival counter
#define OFF_GGEN(g)  (144 + (g) * 16)  // 8 group generation flags

__device__ __forceinline__ float waveReduceSum(float v) {
#pragma unroll
    for (int off = 32; off > 0; off >>= 1) v += __shfl_xor(v, off, 64);
    return v;
}

// Two-level software grid barrier. All inter-block signalling via device-scope
// RMW atomics (plain loads could spin on a stale non-coherent XCD L2 line).
__device__ __forceinline__ void grid_barrier(unsigned* ws32, int bid) {
    __syncthreads();
    if (threadIdx.x == 0) {
        __threadfence();                       // release: h stores visible device-wide
        const int g = bid & 7;
        unsigned* gcnt = ws32 + OFF_GCNT(g);
        unsigned* allc = ws32 + OFF_ALLC;
        unsigned* ggen = ws32 + OFF_GGEN(g);
        const unsigned myGen = atomicAdd(ggen, 0u);   // read gen BEFORE arriving
        __threadfence();                       // order gen-read before arrival RMW
        const unsigned p = atomicAdd(gcnt, 1u);
        if (p == (NBLK / 8) - 1) {             // last arrival in my group
            const unsigned q = atomicAdd(allc, 1u);
            if (q == 7) {                      // last group: release everyone
                atomicExch(allc, 0u);
#pragma unroll
                for (int i = 0; i < 8; ++i) atomicExch(ws32 + OFF_GCNT(i), 0u);
                __threadfence();               // resets visible before gen bumps
#pragma unroll
                for (int i = 0; i < 8; ++i) atomicAdd(ws32 + OFF_GGEN(i), 1u);
            } else {
                while (atomicAdd(ggen, 0u) == myGen) __builtin_amdgcn_s_sleep(1);
            }
        } else {
            while (atomicAdd(ggen, 0u) == myGen) __builtin_amdgcn_s_sleep(1);
        }
        __threadfence();                       // acquire: invalidate stale caches
    }
    __syncthreads();
}

// Wc = W_ih + W_hh (once per launch; halves steady-state weight traffic)
__global__ void __launch_bounds__(NTHR) add_mats(const float4* __restrict__ a,
                                                 const float4* __restrict__ b,
                                                 float4* __restrict__ c, int n4) {
    int i = blockIdx.x * NTHR + threadIdx.x;
    const int stride = gridDim.x * NTHR;
    for (; i < n4; i += stride) {
        float4 x = a[i];
        float4 y = b[i];
        float4 z;
        z.x = x.x + y.x; z.y = x.y + y.y; z.z = x.z + y.z; z.w = x.w + y.w;
        c[i] = z;
    }
}

// Persistent LSTM. Block b owns h-elements [b*EPB, b*EPB+EPB). Wave w (0..3)
// computes gate w's (i,f,g,o) rows for those elements, so the pointwise
// c/h update is block-local; one grid barrier per time step.
__global__ void __launch_bounds__(NTHR, 1) lstm_persistent(
    const float* __restrict__ x0,
    const float* __restrict__ Wih,
    const float* __restrict__ Whh,
    const float* __restrict__ Wc,
    const float* __restrict__ bih,
    const float* __restrict__ bhh,
    const float* __restrict__ Wout,
    const float* __restrict__ bout,
    const int* __restrict__ stepsp,
    float* __restrict__ out,
    float* __restrict__ hwork,
    unsigned* __restrict__ bar,
    int use_wc, int copy_h)
{
    const int tid  = threadIdx.x;
    const int wave = tid >> 6;        // gate index (i,f,g,o)
    const int lane = tid & 63;
    const int bid  = blockIdx.x;
    const int jb   = bid * EPB;

    __shared__ float gsm[4 * EPB];
    __shared__ float csm[EPB];
    if (tid < EPB) csm[tid] = 0.0f;
    __syncthreads();

    const int steps = stepsp[0];

    for (int t = 0; t < steps; ++t) {
        const float* hv = (t == 0) ? x0 : hwork;
        // h fragment in registers; element index matches float4 W loads:
        // element = k*256 + lane*4 + c
        float hr[8][4];
#pragma unroll
        for (int k = 0; k < 8; ++k)
#pragma unroll
            for (int c = 0; c < 4; ++c)
                hr[k][c] = hv[k * 256 + lane * 4 + c];

        float rowsum[EPB];
        if (t == 0 || use_wc) {
            const float* Wm = (t == 0) ? Wih : Wc;   // step 0: h=0 -> only W_ih·x0
#pragma unroll
            for (int e = 0; e < EPB; ++e) {
                const size_t row = (size_t)(wave * HDIM + jb + e);
                const float4* w4 = (const float4*)(Wm + row * HDIM);
                float ax = 0.f, ay = 0.f, az = 0.f, aw = 0.f;
#pragma unroll
                for (int k = 0; k < 8; ++k) {
                    float4 wv = w4[k * 64 + lane];
                    ax += wv.x * hr[k][0];
                    ay += wv.y * hr[k][1];
                    az += wv.z * hr[k][2];
                    aw += wv.w * hr[k][3];
                }
                rowsum[e] = (ax + ay) + (az + aw);
            }
        } else {
            // fallback when d_ws too small for Wc: read both matrices
#pragma unroll
            for (int e = 0; e < EPB; ++e) {
                const size_t row = (size_t)(wave * HDIM + jb + e);
                const float4* wa = (const float4*)(Wih + row * HDIM);
                const float4* wb = (const float4*)(Whh + row * HDIM);
                float ax = 0.f, ay = 0.f, az = 0.f, aw = 0.f;
#pragma unroll
                for (int k = 0; k < 8; ++k) {
                    float4 u = wa[k * 64 + lane];
                    float4 v = wb[k * 64 + lane];
                    ax += (u.x + v.x) * hr[k][0];
                    ay += (u.y + v.y) * hr[k][1];
                    az += (u.z + v.z) * hr[k][2];
                    aw += (u.w + v.w) * hr[k][3];
                }
                rowsum[e] = (ax + ay) + (az + aw);
            }
        }

#pragma unroll
        for (int e = 0; e < EPB; ++e) {
            float s = waveReduceSum(rowsum[e]);
            if (lane == 0) {
                const int row = wave * HDIM + jb + e;
                gsm[wave * EPB + e] = s + bih[row] + bhh[row];
            }
        }
        __syncthreads();

        if (tid < EPB) {
            float gi = gsm[0 * EPB + tid];
            float gf = gsm[1 * EPB + tid];
            float gg = gsm[2 * EPB + tid];
            float go = gsm[3 * EPB + tid];
            float si = 1.0f / (1.0f + expf(-gi));
            float sf = 1.0f / (1.0f + expf(-gf));
            float tg = tanhf(gg);
            float so = 1.0f / (1.0f + expf(-go));
            float c  = sf * csm[tid] + si * tg;
            csm[tid] = c;
            hwork[jb + tid] = so * tanhf(c);
        }
        grid_barrier(bar, bid);
    }

    // final c
    if (tid < EPB) out[NCLS + HDIM + jb + tid] = csm[tid];

    // block 0: logits + softmax (+ h copy when hwork lives in d_ws)
    if (bid == 0) {
        __shared__ float lsm[NCLS];
        float hr[8][4];
#pragma unroll
        for (int k = 0; k < 8; ++k)
#pragma unroll
            for (int c = 0; c < 4; ++c)
                hr[k][c] = hwork[k * 256 + lane * 4 + c];
        for (int r = wave; r < NCLS; r += 4) {
            const float4* w4 = (const float4*)(Wout + (size_t)r * HDIM);
            float ax = 0.f, ay = 0.f, az = 0.f, aw = 0.f;
#pragma unroll
            for (int k = 0; k < 8; ++k) {
                float4 wv = w4[k * 64 + lane];
                ax += wv.x * hr[k][0];
                ay += wv.y * hr[k][1];
                az += wv.z * hr[k][2];
                aw += wv.w * hr[k][3];
            }
            float s = waveReduceSum((ax + ay) + (az + aw));
            if (lane == 0) lsm[r] = s + bout[r];
        }
        __syncthreads();
        if (tid == 0) {
            float m = lsm[0];
            for (int r = 1; r < NCLS; ++r) m = fmaxf(m, lsm[r]);
            float ex[NCLS];
            float den = 0.0f;
            for (int r = 0; r < NCLS; ++r) { ex[r] = expf(lsm[r] - m); den += ex[r]; }
            float inv = 1.0f / den;
            for (int r = 0; r < NCLS; ++r) out[r] = ex[r] * inv;
        }
        if (copy_h) {
            for (int i = tid; i < HDIM; i += NTHR) out[NCLS + i] = hwork[i];
        }
    }
}

extern "C" void kernel_launch(void* const* d_in, const int* in_sizes, int n_in,
                              void* d_out, int out_size, void* d_ws, size_t ws_size,
                              hipStream_t stream) {
    const float* x0    = (const float*)d_in[0];   // only row 0 of inputs is used
    const float* Wih   = (const float*)d_in[1];
    const float* Whh   = (const float*)d_in[2];
    const float* bih   = (const float*)d_in[3];
    const float* bhh   = (const float*)d_in[4];
    const float* Wout  = (const float*)d_in[5];
    const float* bout  = (const float*)d_in[6];
    const int*   steps = (const int*)d_in[7];
    float* out = (float*)d_out;

    // reset barrier state every launch (graph-capture safe, deterministic)
    hipMemsetAsync(d_ws, 0, BAR_BYTES, stream);

    float* hwork;
    int copy_h;
    if (ws_size >= BAR_BYTES + HDIM * sizeof(float)) {
        hwork = (float*)((char*)d_ws + BAR_BYTES);
        copy_h = 1;
    } else {
        hwork = out + NCLS;                  // degenerate: h lives in the output
        copy_h = 0;
    }

    const size_t wc_off   = 16384;
    const size_t wc_bytes = (size_t)4 * HDIM * HDIM * sizeof(float);  // 64 MiB
    float* Wc = (float*)((char*)d_ws + wc_off);
    const int use_wc = (ws_size >= wc_off + wc_bytes) ? 1 : 0;

    if (use_wc) {
        const int n4 = 4 * HDIM * HDIM / 4;
        add_mats<<<dim3(1024), dim3(NTHR), 0, stream>>>(
            (const float4*)Wih, (const float4*)Whh, (float4*)Wc, n4);
    }

    lstm_persistent<<<dim3(NBLK), dim3(NTHR), 0, stream>>>(
        x0, Wih, Whh, Wc, bih, bhh, Wout, bout, steps, out, hwork,
        (unsigned*)d_ws, use_wc, copy_h);
}

// Round 3
// 8521.005 us; speedup vs baseline: 1.7523x; 1.7523x over previous
//
#include <hip/hip_runtime.h>
#include <cstdint>
#include <cstddef>

#define HDIM 2048
#define NCLS 11
#define NBLK 256
#define NTHR 256
#define EPB  (HDIM / NBLK)      // 8 h-elements per block
#define CHUNK 256               // h-columns per lane (weights held in VGPRs)
#define CPAD  260               // padded chunk stride in LDS floats (bank stagger)

// d_ws layout: [0,4096) barrier state (memset each launch); [4096,12288) hwork
#define BAR_BYTES 4096
#define OFF_GCNT(g)  ((g) * 16)
#define OFF_ALLC     (128)
#define OFF_GGEN(g)  (144 + (g) * 16)

// Two-level software grid barrier (proven in Round 2). Device-scope RMW
// atomics for all signalling; fences for h-store release / acquire.
__device__ __forceinline__ void grid_barrier(unsigned* ws32, int bid) {
    __syncthreads();
    if (threadIdx.x == 0) {
        __threadfence();
        const int g = bid & 7;
        unsigned* gcnt = ws32 + OFF_GCNT(g);
        unsigned* allc = ws32 + OFF_ALLC;
        unsigned* ggen = ws32 + OFF_GGEN(g);
        const unsigned myGen = atomicAdd(ggen, 0u);
        __threadfence();
        const unsigned p = atomicAdd(gcnt, 1u);
        if (p == (NBLK / 8) - 1) {
            const unsigned q = atomicAdd(allc, 1u);
            if (q == 7) {
                atomicExch(allc, 0u);
#pragma unroll
                for (int i = 0; i < 8; ++i) atomicExch(ws32 + OFF_GCNT(i), 0u);
                __threadfence();
#pragma unroll
                for (int i = 0; i < 8; ++i) atomicAdd(ws32 + OFF_GGEN(i), 1u);
            } else {
                while (atomicAdd(ggen, 0u) == myGen) __builtin_amdgcn_s_sleep(2);
            }
        } else {
            while (atomicAdd(ggen, 0u) == myGen) __builtin_amdgcn_s_sleep(2);
        }
        __threadfence();
    }
    __syncthreads();
}

__device__ __forceinline__ float waveReduceSum(float v) {
#pragma unroll
    for (int off = 32; off > 0; off >>= 1) v += __shfl_xor(v, off, 64);
    return v;
}

// Weight-stationary persistent LSTM. Each lane holds 256 fp32 weights in
// VGPRs (64 MiB total across the chip = half the aggregate register file).
// Block b owns h[b*8 .. b*8+8); wave w = gate w; lane (r=lane>>3, cc=lane&7)
// owns row w*2048+b*8+r, columns [cc*256, cc*256+256).
__global__ void __launch_bounds__(NTHR, 1) lstm_persistent(
    const float* __restrict__ x0,
    const float* __restrict__ Wih,
    const float* __restrict__ Whh,
    const float* __restrict__ bih,
    const float* __restrict__ bhh,
    const float* __restrict__ Wout,
    const float* __restrict__ bout,
    const int* __restrict__ stepsp,
    float* __restrict__ out,
    float* __restrict__ hwork,
    unsigned* __restrict__ bar,
    int copy_h)
{
    const int tid  = threadIdx.x;
    const int wave = tid >> 6;          // gate (i,f,g,o)
    const int lane = tid & 63;
    const int rl   = lane >> 3;         // row within gate for this block
    const int cc   = lane & 7;          // column chunk
    const int bid  = blockIdx.x;
    const int jb   = bid * EPB;

    __shared__ float hlds[8 * CPAD];    // 8 chunks, padded for bank stagger
    __shared__ float gsm[4 * EPB];
    __shared__ float csm[EPB];

    const int row = wave * HDIM + jb + rl;
    const size_t sbase = (size_t)row * HDIM + (size_t)cc * CHUNK;

    // ---- prefill: w = W_ih slice (step 0 uses W_ih alone since h0 = 0) ----
    float w[CHUNK];
#pragma unroll
    for (int jj = 0; jj < 64; ++jj) {
        float4 v = *(const float4*)(Wih + sbase + (size_t)jj * 4);
        w[4 * jj + 0] = v.x; w[4 * jj + 1] = v.y;
        w[4 * jj + 2] = v.z; w[4 * jj + 3] = v.w;
    }
    const float bsum = bih[row] + bhh[row];
    if (tid < EPB) csm[tid] = 0.0f;

    const int steps = stepsp[0];
    // LDS staging offsets: element e -> hlds[(e>>8)*CPAD + (e&255)]
    const int e0   = tid * 8;
    const int soff = (tid >> 5) * CPAD + (tid & 31) * 8;

    for (int t = 0; t < steps; ++t) {
        if (t == 0) {
#pragma unroll
            for (int i = 0; i < 8; ++i) hlds[soff + i] = x0[e0 + i];
        } else {
#pragma unroll
            for (int i = 0; i < 8; ++i)
                hlds[soff + i] = __hip_atomic_load(
                    (const float*)&hwork[e0 + i],
                    __ATOMIC_RELAXED, __HIP_MEMORY_SCOPE_AGENT);
        }
        __syncthreads();

        // dot: 256 reg-weights x LDS-broadcast h chunk
        const float* hc = &hlds[cc * CPAD];
        float ax = 0.f, ay = 0.f, az = 0.f, aw = 0.f;
#pragma unroll
        for (int jj = 0; jj < 64; ++jj) {
            float4 hv = *(const float4*)(hc + jj * 4);
            ax += w[4 * jj + 0] * hv.x;
            ay += w[4 * jj + 1] * hv.y;
            az += w[4 * jj + 2] * hv.z;
            aw += w[4 * jj + 3] * hv.w;
        }
        float part = (ax + ay) + (az + aw);
        part += __shfl_xor(part, 1, 64);
        part += __shfl_xor(part, 2, 64);
        part += __shfl_xor(part, 4, 64);        // summed over cc
        if (cc == 0) gsm[wave * EPB + rl] = part + bsum;
        __syncthreads();

        if (tid < EPB) {
            float gi = gsm[0 * EPB + tid];
            float gf = gsm[1 * EPB + tid];
            float gg = gsm[2 * EPB + tid];
            float go = gsm[3 * EPB + tid];
            float si = 1.0f / (1.0f + expf(-gi));
            float sf = 1.0f / (1.0f + expf(-gf));
            float tg = tanhf(gg);
            float so = 1.0f / (1.0f + expf(-go));
            float c  = sf * csm[tid] + si * tg;
            csm[tid] = c;
            __hip_atomic_store(&hwork[jb + tid], so * tanhf(c),
                               __ATOMIC_RELAXED, __HIP_MEMORY_SCOPE_AGENT);
        }

        if (t == 0) {
            // switch weights to Wc = W_ih + W_hh for steps >= 1
#pragma unroll
            for (int jj = 0; jj < 64; ++jj) {
                float4 v = *(const float4*)(Whh + sbase + (size_t)jj * 4);
                w[4 * jj + 0] += v.x; w[4 * jj + 1] += v.y;
                w[4 * jj + 2] += v.z; w[4 * jj + 3] += v.w;
            }
        }
        grid_barrier(bar, bid);
    }

    // final c
    if (tid < EPB) out[NCLS + HDIM + jb + tid] = csm[tid];

    // block 0: stage final h, then logits + softmax + h copy
    if (bid == 0) {
#pragma unroll
        for (int i = 0; i < 8; ++i)
            hlds[soff + i] = __hip_atomic_load(
                (const float*)&hwork[e0 + i],
                __ATOMIC_RELAXED, __HIP_MEMORY_SCOPE_AGENT);
        __syncthreads();

        __shared__ float lsm[NCLS];
        float hr[8][4];
#pragma unroll
        for (int k = 0; k < 8; ++k)
#pragma unroll
            for (int c = 0; c < 4; ++c)
                hr[k][c] = hlds[k * CPAD + lane * 4 + c];
        for (int r = wave; r < NCLS; r += 4) {
            const float4* w4 = (const float4*)(Wout + (size_t)r * HDIM);
            float sx = 0.f, sy = 0.f, sz = 0.f, sw = 0.f;
#pragma unroll
            for (int k = 0; k < 8; ++k) {
                float4 wv = w4[k * 64 + lane];
                sx += wv.x * hr[k][0];
                sy += wv.y * hr[k][1];
                sz += wv.z * hr[k][2];
                sw += wv.w * hr[k][3];
            }
            float s = waveReduceSum((sx + sy) + (sz + sw));
            if (lane == 0) lsm[r] = s + bout[r];
        }
        __syncthreads();
        if (tid == 0) {
            float m = lsm[0];
            for (int r = 1; r < NCLS; ++r) m = fmaxf(m, lsm[r]);
            float ex[NCLS];
            float den = 0.0f;
            for (int r = 0; r < NCLS; ++r) { ex[r] = expf(lsm[r] - m); den += ex[r]; }
            float inv = 1.0f / den;
            for (int r = 0; r < NCLS; ++r) out[r] = ex[r] * inv;
        }
        if (copy_h) {
#pragma unroll
            for (int i = 0; i < 8; ++i)
                out[NCLS + e0 + i] = hlds[soff + i];
        }
    }
}

extern "C" void kernel_launch(void* const* d_in, const int* in_sizes, int n_in,
                              void* d_out, int out_size, void* d_ws, size_t ws_size,
                              hipStream_t stream) {
    const float* x0    = (const float*)d_in[0];   // row 0 of inputs
    const float* Wih   = (const float*)d_in[1];
    const float* Whh   = (const float*)d_in[2];
    const float* bih   = (const float*)d_in[3];
    const float* bhh   = (const float*)d_in[4];
    const float* Wout  = (const float*)d_in[5];
    const float* bout  = (const float*)d_in[6];
    const int*   steps = (const int*)d_in[7];
    float* out = (float*)d_out;

    hipMemsetAsync(d_ws, 0, BAR_BYTES, stream);   // reset barrier state

    float* hwork;
    int copy_h;
    if (ws_size >= BAR_BYTES + HDIM * sizeof(float)) {
        hwork = (float*)((char*)d_ws + BAR_BYTES);
        copy_h = 1;
    } else {
        hwork = out + NCLS;
        copy_h = 0;
    }

    lstm_persistent<<<dim3(NBLK), dim3(NTHR), 0, stream>>>(
        x0, Wih, Whh, bih, bhh, Wout, bout, steps, out, hwork,
        (unsigned*)d_ws, copy_h);
}

// Round 4
// 8412.380 us; speedup vs baseline: 1.7749x; 1.0129x over previous
//
#include <hip/hip_runtime.h>
#include <cstdint>
#include <cstddef>

#define HDIM 2048
#define NCLS 11
#define NBLK 256
#define NTHR 256
#define EPB  (HDIM / NBLK)      // 8 h-elements per block
#define CHUNK 256               // h-columns per lane (weights in VGPR/AGPR)
#define CPAD  260               // padded chunk stride in LDS floats

// d_ws: two generation-tagged h-slot buffers (parity = step & 1).
// Slot b (64 B when sw=16): { h[8] (f32), gen (u32), pad }. memset each launch.

__device__ __forceinline__ float waveReduceSum(float v) {
#pragma unroll
    for (int off = 32; off > 0; off >>= 1) v += __shfl_xor(v, off, 64);
    return v;
}

// Weight-stationary persistent LSTM, barrier-free.
// Block b owns h[b*8..b*8+8); wave w = gate w; lane (rl=lane>>3, cc=lane&7)
// owns row w*2048+b*8+rl, columns [cc*256, cc*256+256) held in registers.
// Cross-block h exchange via per-block gen-tagged slots (release/acquire).
__global__ void __launch_bounds__(NTHR, 1) lstm_persistent(
    const float* __restrict__ x0,
    const float* __restrict__ Wih,
    const float* __restrict__ Whh,
    const float* __restrict__ bih,
    const float* __restrict__ bhh,
    const float* __restrict__ Wout,
    const float* __restrict__ bout,
    const int* __restrict__ stepsp,
    float* __restrict__ out,
    float* __restrict__ tag0,
    float* __restrict__ tag1,
    int sw)                      // slot stride in floats (>= 9)
{
    const int tid  = threadIdx.x;
    const int wave = tid >> 6;          // gate (i,f,g,o)
    const int lane = tid & 63;
    const int rl   = lane >> 3;         // row within gate for this block
    const int cc   = lane & 7;          // column chunk
    const int bid  = blockIdx.x;
    const int jb   = bid * EPB;

    __shared__ float hlds[8 * CPAD];
    __shared__ float gsm[4 * EPB];
    __shared__ float csm[EPB];

    const int row = wave * HDIM + jb + rl;
    const size_t sbase = (size_t)row * HDIM + (size_t)cc * CHUNK;

    // prefill: w = W_ih slice (step 0 uses W_ih alone since h0 = 0)
    float w[CHUNK];
#pragma unroll
    for (int jj = 0; jj < 64; ++jj) {
        float4 v = *(const float4*)(Wih + sbase + (size_t)jj * 4);
        w[4 * jj + 0] = v.x; w[4 * jj + 1] = v.y;
        w[4 * jj + 2] = v.z; w[4 * jj + 3] = v.w;
    }
    const float bsum = bih[row] + bhh[row];
    if (tid < EPB) csm[tid] = 0.0f;

    const int steps = stepsp[0];
    const int e0   = tid * 8;                              // h elements this thread stages
    const int soff = (tid >> 5) * CPAD + (tid & 31) * 8;   // LDS address of e0

    for (int t = 0; t < steps; ++t) {
        if (t == 0) {
#pragma unroll
            for (int i = 0; i < 8; ++i) hlds[soff + i] = x0[e0 + i];
        } else {
            float* tb   = (t & 1) ? tag1 : tag0;
            float* slot = tb + (size_t)tid * sw;            // thread tid <-> producer block tid
            unsigned* genp = (unsigned*)(slot + 8);
            while (__hip_atomic_load(genp, __ATOMIC_RELAXED, __HIP_MEMORY_SCOPE_AGENT)
                   < (unsigned)t)
                __builtin_amdgcn_s_sleep(1);
            (void)__hip_atomic_load(genp, __ATOMIC_ACQUIRE, __HIP_MEMORY_SCOPE_AGENT);
#pragma unroll
            for (int i = 0; i < 8; ++i)
                hlds[soff + i] = __hip_atomic_load(slot + i, __ATOMIC_RELAXED,
                                                   __HIP_MEMORY_SCOPE_AGENT);
        }
        __syncthreads();

        // dot: 256 register weights x LDS-broadcast h chunk
        const float* hc = &hlds[cc * CPAD];
        float ax = 0.f, ay = 0.f, az = 0.f, aw = 0.f;
#pragma unroll
        for (int jj = 0; jj < 64; ++jj) {
            float4 hv = *(const float4*)(hc + jj * 4);
            ax += w[4 * jj + 0] * hv.x;
            ay += w[4 * jj + 1] * hv.y;
            az += w[4 * jj + 2] * hv.z;
            aw += w[4 * jj + 3] * hv.w;
        }
        float part = (ax + ay) + (az + aw);
        part += __shfl_xor(part, 1, 64);
        part += __shfl_xor(part, 2, 64);
        part += __shfl_xor(part, 4, 64);        // summed over cc
        if (cc == 0) gsm[wave * EPB + rl] = part + bsum;
        __syncthreads();

        float* wbuf = ((t + 1) & 1) ? tag1 : tag0;
        float* wslot = wbuf + (size_t)bid * sw;
        if (tid < EPB) {
            float gi = gsm[0 * EPB + tid];
            float gf = gsm[1 * EPB + tid];
            float gg = gsm[2 * EPB + tid];
            float go = gsm[3 * EPB + tid];
            float si = 1.0f / (1.0f + expf(-gi));
            float sf = 1.0f / (1.0f + expf(-gf));
            float tg = tanhf(gg);
            float so = 1.0f / (1.0f + expf(-go));
            float c  = sf * csm[tid] + si * tg;
            csm[tid] = c;
            __hip_atomic_store(wslot + tid, so * tanhf(c),
                               __ATOMIC_RELAXED, __HIP_MEMORY_SCOPE_AGENT);
        }
        __syncthreads();                        // h stores done before tag
        if (tid == 0)
            __hip_atomic_store((unsigned*)(wslot + 8), (unsigned)(t + 1),
                               __ATOMIC_RELEASE, __HIP_MEMORY_SCOPE_AGENT);

        if (t == 0) {
            // switch weights to Wc = W_ih + W_hh for steps >= 1
#pragma unroll
            for (int jj = 0; jj < 64; ++jj) {
                float4 v = *(const float4*)(Whh + sbase + (size_t)jj * 4);
                w[4 * jj + 0] += v.x; w[4 * jj + 1] += v.y;
                w[4 * jj + 2] += v.z; w[4 * jj + 3] += v.w;
            }
        }
    }

    // final c
    if (tid < EPB) out[NCLS + HDIM + jb + tid] = csm[tid];

    // block 0: gather final h (gen == steps), classifier head + h copy
    if (bid == 0) {
        float* tb   = (steps & 1) ? tag1 : tag0;
        float* slot = tb + (size_t)tid * sw;
        unsigned* genp = (unsigned*)(slot + 8);
        while (__hip_atomic_load(genp, __ATOMIC_RELAXED, __HIP_MEMORY_SCOPE_AGENT)
               < (unsigned)steps)
            __builtin_amdgcn_s_sleep(1);
        (void)__hip_atomic_load(genp, __ATOMIC_ACQUIRE, __HIP_MEMORY_SCOPE_AGENT);
#pragma unroll
        for (int i = 0; i < 8; ++i)
            hlds[soff + i] = __hip_atomic_load(slot + i, __ATOMIC_RELAXED,
                                               __HIP_MEMORY_SCOPE_AGENT);
        __syncthreads();

        __shared__ float lsm[NCLS];
        float hr[8][4];
#pragma unroll
        for (int k = 0; k < 8; ++k)
#pragma unroll
            for (int c = 0; c < 4; ++c)
                hr[k][c] = hlds[k * CPAD + lane * 4 + c];
        for (int r = wave; r < NCLS; r += 4) {
            const float4* w4 = (const float4*)(Wout + (size_t)r * HDIM);
            float sx = 0.f, sy = 0.f, sz = 0.f, sw4 = 0.f;
#pragma unroll
            for (int k = 0; k < 8; ++k) {
                float4 wv = w4[k * 64 + lane];
                sx += wv.x * hr[k][0];
                sy += wv.y * hr[k][1];
                sz += wv.z * hr[k][2];
                sw4 += wv.w * hr[k][3];
            }
            float s = waveReduceSum((sx + sy) + (sz + sw4));
            if (lane == 0) lsm[r] = s + bout[r];
        }
        __syncthreads();
        if (tid == 0) {
            float m = lsm[0];
            for (int r = 1; r < NCLS; ++r) m = fmaxf(m, lsm[r]);
            float ex[NCLS];
            float den = 0.0f;
            for (int r = 0; r < NCLS; ++r) { ex[r] = expf(lsm[r] - m); den += ex[r]; }
            float inv = 1.0f / den;
            for (int r = 0; r < NCLS; ++r) out[r] = ex[r] * inv;
        }
#pragma unroll
        for (int i = 0; i < 8; ++i)
            out[NCLS + e0 + i] = hlds[soff + i];
    }
}

extern "C" void kernel_launch(void* const* d_in, const int* in_sizes, int n_in,
                              void* d_out, int out_size, void* d_ws, size_t ws_size,
                              hipStream_t stream) {
    const float* x0    = (const float*)d_in[0];   // row 0 of inputs
    const float* Wih   = (const float*)d_in[1];
    const float* Whh   = (const float*)d_in[2];
    const float* bih   = (const float*)d_in[3];
    const float* bhh   = (const float*)d_in[4];
    const float* Wout  = (const float*)d_in[5];
    const float* bout  = (const float*)d_in[6];
    const int*   steps = (const int*)d_in[7];
    float* out = (float*)d_out;

    // slot stride: 16 floats (64 B, line-aligned) if workspace allows, else 9
    int sw = 16;
    size_t need = (size_t)2 * NBLK * sw * sizeof(float);   // 32 KiB
    if (ws_size < need) { sw = 9; need = (size_t)2 * NBLK * sw * sizeof(float); }

    float* tag0 = (float*)d_ws;
    float* tag1 = tag0 + (size_t)NBLK * sw;

    // reset generation tags each launch (graph-capture safe, deterministic)
    hipMemsetAsync(d_ws, 0, need, stream);

    lstm_persistent<<<dim3(NBLK), dim3(NTHR), 0, stream>>>(
        x0, Wih, Whh, bih, bhh, Wout, bout, steps, out, tag0, tag1, sw);
}